// Round 17
// baseline (428.527 us; speedup 1.0000x reference)
//
#include <hip/hip_runtime.h>
#include <math.h>

typedef unsigned short ushort_t;
typedef unsigned int uint_t;
typedef __attribute__((ext_vector_type(8))) short short8_t;   // 8 bf16 (4 VGPR)
typedef __attribute__((ext_vector_type(4))) float f32x4_t;    // MFMA accumulator

constexpr int Bb = 32, Ll = 64, Nn = 8;
constexpr int IMGS = Bb * Ll * Nn;          // 16384
constexpr int Cc = 3, Hh = 40, Ww = 40;
constexpr int HID = 64, G3 = 192, NACT = 8;
constexpr int CGRID = 1024;                 // persistent conv12 blocks (4/CU)
constexpr int NITER = (IMGS / 2) / CGRID;   // 8 tiles (2 images each) per block

__device__ inline float bf2f(ushort_t u) {
  union { uint_t i; float f; } v; v.i = ((uint_t)u) << 16; return v.f;
}
__device__ inline ushort_t f2bf(float f) {   // RNE
  union { float f; uint_t u; } v; v.f = f;
  uint_t r = v.u + 0x7fffu + ((v.u >> 16) & 1u);
  return (ushort_t)(r >> 16);
}
__device__ inline void unpack2(uint_t u, float& lo, float& hi) {
  union { uint_t i; float f; } a, b;
  a.i = u << 16; b.i = u & 0xffff0000u;
  lo = a.f; hi = b.f;
}
__device__ inline float ld1(const void* p, int idx, int isbf) {
  return isbf ? bf2f(((const ushort_t*)p)[idx]) : ((const float*)p)[idx];
}
__device__ inline short8_t ldsh8(const ushort_t* p) {   // 16B from LDS (8B aligned)
  union { short8_t v; uint2 u[2]; } r;
  r.u[0] = *(const uint2*)p;
  r.u[1] = *(const uint2*)(p + 4);
  return r.v;
}
__device__ inline short8_t ldg8(const ushort_t* p) {    // 16B global
  union { short8_t v; uint4 u; } r;
  r.u = *(const uint4*)p;
  return r.v;
}
#define WAVE_FENCE() asm volatile("s_waitcnt lgkmcnt(0)" ::: "memory")

// ---------------- dtype detect (insurance) ----------------
__global__ __launch_bounds__(256) void detect_kernel(
    const ushort_t* __restrict__ obs, const ushort_t* __restrict__ whh,
    int* __restrict__ flags) {
  __shared__ int cnt[2];
  if (threadIdx.x < 2) cnt[threadIdx.x] = 0;
  __syncthreads();
  int bad0 = 0, bad1 = 0;
  for (int i = threadIdx.x; i < 4096; i += 256) {
    int e0 = (obs[i] >> 7) & 0xFF; if (e0 >= 0xC0) bad0++;
    int e1 = (whh[i] >> 7) & 0xFF; if (e1 >= 0xC0) bad1++;
  }
  atomicAdd(&cnt[0], bad0);
  atomicAdd(&cnt[1], bad1);
  __syncthreads();
  if (threadIdx.x == 0) { flags[0] = (cnt[0] <= 4); flags[1] = (cnt[1] <= 4); }
}

// ---------------- weight repack -> bf16 (verified R5-R16) ----------------
__global__ __launch_bounds__(256) void repack_kernel(
    const void* __restrict__ w1, const void* __restrict__ w2,
    const void* __restrict__ w3, const void* __restrict__ wih,
    const int* __restrict__ flags,
    ushort_t* __restrict__ w1pack, ushort_t* __restrict__ w2pack,
    ushort_t* __restrict__ w3bf, ushort_t* __restrict__ wihb) {
  const int fw = flags[1];
  int t = blockIdx.x * 256 + threadIdx.x;
  if (t < 6144) w1pack[t] = f2bf(ld1(w1, t, fw));
  if (t < 32768) {
    int oc = t >> 9, r = t & 511;
    int kykx = r >> 5, ic = r & 31;
    w2pack[t] = f2bf(ld1(w2, oc * 512 + ic * 16 + kykx, fw));
  }
  if (t < 36864) w3bf[t] = f2bf(ld1(w3, t, fw));
  if (t < 12288) wihb[t] = f2bf(ld1(wih, t, fw));
}

// ---------------- persistent double-buffered conv1+conv2, 2 images/tile ----------------
// buf[c][im][0..4799] ushort: bf16 obs -> f1 alias (<=3231); tail [3232..3807]: f2.
// Budgets: LDS 2x2x9.6KB = 38.4KB (4 blocks/CU); prefetch 10 float4 = 40 VGPR (<128).
__global__ __launch_bounds__(256, 4) void conv12_kernel(
    const void* __restrict__ obs, const ushort_t* __restrict__ w1pack,
    const ushort_t* __restrict__ w2pack,
    const void* __restrict__ b1, const void* __restrict__ b2,
    const int* __restrict__ flags, ushort_t* __restrict__ f2g) {
  __shared__ __attribute__((aligned(16))) ushort_t s_mem[2][2][4800];   // 38.4 KB

  const int tid = threadIdx.x;
  const int wave = tid >> 6, lane = tid & 63;
  const int lrow = lane & 15, lk8 = lane >> 4;
  const int im = wave >> 1, half = wave & 1;          // conv1: image, m-half
  const int fobs = flags[0], fw = flags[1];

  // conv1 A-row offsets for this wave's half (constant across tiles)
  int ab[3];
#pragma unroll
  for (int t = 0; t < 3; ++t) {
    int p = (half * 3 + t) * 16 + lrow; if (p > 80) p = 80;
    ab[t] = (p / 9) * 160 + (p % 9) * 4;
  }
  const float bz0 = ld1(b1, lrow, fw), bz1 = ld1(b1, 16 + lrow, fw);
  // conv2 row mapping (M = 2 img x 9 pix = 18 rows, 2 m-tiles)
  int imgr[2], pbx[2];
#pragma unroll
  for (int mt = 0; mt < 2; ++mt) {
    int row = mt * 16 + lrow; if (row > 17) row = 17;
    const int ir = row / 9, p2 = row - ir * 9;
    imgr[mt] = ir;
    pbx[mt] = (p2 / 3) * 18 + (p2 % 3) * 2;           // (oy*2)*9 + ox*2
  }
  const ushort_t* w1r = w1pack + lrow * 192 + lk8 * 8;
  const ushort_t* w2r = w2pack + (wave * 16 + lrow) * 512 + lk8 * 8;
  const float b2v = ld1(b2, wave * 16 + lrow, fw);

  // ---- prologue: stage tile(it=0) into buf 0 ----
  {
    const size_t base = (size_t)blockIdx.x * 2 * 4800;
    if (fobs) {
      const uint4* src = reinterpret_cast<const uint4*>((const ushort_t*)obs + base);
#pragma unroll
      for (int t2 = 0; t2 < 5; ++t2) {                 // 1200 uint4
        const int i = t2 * 256 + tid;
        if (i < 1200) reinterpret_cast<uint4*>(&s_mem[0][i / 600][0])[i % 600] = src[i];
      }
    } else {
      const float4* src = reinterpret_cast<const float4*>((const float*)obs + base);
#pragma unroll
      for (int t2 = 0; t2 < 10; ++t2) {                // 2400 float4
        const int i = t2 * 256 + tid;
        if (i < 2400) {
          float4 v = src[i];
          uint2 o;
          o.x = (uint_t)f2bf(v.x) | ((uint_t)f2bf(v.y) << 16);
          o.y = (uint_t)f2bf(v.z) | ((uint_t)f2bf(v.w) << 16);
          reinterpret_cast<uint2*>(&s_mem[0][i / 1200][0])[i % 1200] = o;
        }
      }
    }
  }
  __syncthreads();

  for (int it = 0; it < NITER; ++it) {
    const int c = it & 1;
    const int img0 = (blockIdx.x + it * CGRID) * 2;
    const bool has_next = (it + 1 < NITER);
    const size_t nbase = has_next ? (size_t)(blockIdx.x + (it + 1) * CGRID) * 2 * 4800 : 0;

    // ---- issue next tile's loads NOW (held in registers through conv1+conv2) ----
    uint4 rb[5];
    float4 rf[10];
    if (has_next) {
      if (fobs) {
        const uint4* src = reinterpret_cast<const uint4*>((const ushort_t*)obs + nbase);
#pragma unroll
        for (int t2 = 0; t2 < 5; ++t2) { const int i = t2 * 256 + tid; rb[t2] = src[i < 1200 ? i : 1199]; }
      } else {
        const float4* src = reinterpret_cast<const float4*>((const float*)obs + nbase);
#pragma unroll
        for (int t2 = 0; t2 < 10; ++t2) { const int i = t2 * 256 + tid; rf[t2] = src[i < 2400 ? i : 2399]; }
      }
    }

    // ---- conv1: 2 waves per image, M-half = 48 rows, N=32, K=192 ----
    ushort_t* si = &s_mem[c][im][0];
    f32x4_t a1c[2][3];
#pragma unroll
    for (int nt = 0; nt < 2; ++nt)
#pragma unroll
      for (int t = 0; t < 3; ++t) a1c[nt][t] = (f32x4_t){0.f, 0.f, 0.f, 0.f};
#pragma unroll
    for (int ks = 0; ks < 6; ++ks) {
      const int g = ks * 4 + lk8;                       // k-octet 0..23
      const int aoff = (g >> 3) * 1600 + (g & 7) * 40;  // ic*1600 + ky*40
      short8_t b0 = ldg8(w1r + ks * 32);
      short8_t b1v = ldg8(w1r + 16 * 192 + ks * 32);
#pragma unroll
      for (int t = 0; t < 3; ++t) {
        short8_t a = ldsh8(&si[aoff + ab[t]]);
        a1c[0][t] = __builtin_amdgcn_mfma_f32_16x16x32_bf16(a, b0, a1c[0][t], 0, 0, 0);
        a1c[1][t] = __builtin_amdgcn_mfma_f32_16x16x32_bf16(a, b1v, a1c[1][t], 0, 0, 0);
      }
    }
    __syncthreads();   // ALL waves' obs reads done (2 waves share each image buffer)
#pragma unroll
    for (int t = 0; t < 3; ++t) {
#pragma unroll
      for (int r = 0; r < 4; ++r) {
        const int p = (half * 3 + t) * 16 + lk8 * 4 + r;
        if (p < 81) {
          si[p * 40 + lrow]      = f2bf(fmaxf(a1c[0][t][r] + bz0, 0.f));
          si[p * 40 + 16 + lrow] = f2bf(fmaxf(a1c[1][t][r] + bz1, 0.f));
        }
      }
    }
    __syncthreads();   // f1 complete & visible

    // ---- conv2: M=18(pad32) x N=16 (wave's oc-tile) x K=512 ----
    {
      f32x4_t acc[2];
#pragma unroll
      for (int mt = 0; mt < 2; ++mt) acc[mt] = (f32x4_t){0.f, 0.f, 0.f, 0.f};
#pragma unroll
      for (int s = 0; s < 16; ++s) {                    // s = ky*4+kx
        const int po = (s >> 2) * 9 + (s & 3);
        short8_t bv = ldg8(w2r + s * 32);
        short8_t a0 = ldsh8(&s_mem[c][imgr[0]][(pbx[0] + po) * 40 + lk8 * 8]);
        short8_t a1 = ldsh8(&s_mem[c][imgr[1]][(pbx[1] + po) * 40 + lk8 * 8]);
        acc[0] = __builtin_amdgcn_mfma_f32_16x16x32_bf16(a0, bv, acc[0], 0, 0, 0);
        acc[1] = __builtin_amdgcn_mfma_f32_16x16x32_bf16(a1, bv, acc[1], 0, 0, 0);
      }
      const int oc = wave * 16 + lrow;
#pragma unroll
      for (int mt = 0; mt < 2; ++mt) {
#pragma unroll
        for (int r = 0; r < 4; ++r) {
          const int row = mt * 16 + lk8 * 4 + r;
          if (row < 18) {
            const int ir = row / 9, pp = row - ir * 9;
            s_mem[c][ir][3232 + oc * 9 + pp] = f2bf(fmaxf(acc[mt][r] + b2v, 0.f));
          }
        }
      }
    }
    __syncthreads();   // f2 tails visible

    // ---- coalesced f2 -> global (144 uint4) ----
    if (tid < 144) {
      const int im_ = tid / 72, off = tid - im_ * 72;
      *reinterpret_cast<uint4*>(&f2g[(size_t)(img0 + im_) * 576 + off * 8]) =
          *reinterpret_cast<const uint4*>(&s_mem[c][im_][3232 + off * 8]);
    }

    // ---- write staged registers into other buffer (disjoint from tail reads) ----
    if (has_next) {
      const int nc = c ^ 1;
      if (fobs) {
#pragma unroll
        for (int t2 = 0; t2 < 5; ++t2) {
          const int i = t2 * 256 + tid;
          if (i < 1200) reinterpret_cast<uint4*>(&s_mem[nc][i / 600][0])[i % 600] = rb[t2];
        }
      } else {
#pragma unroll
        for (int t2 = 0; t2 < 10; ++t2) {
          const int i = t2 * 256 + tid;
          if (i < 2400) {
            uint2 o;
            o.x = (uint_t)f2bf(rf[t2].x) | ((uint_t)f2bf(rf[t2].y) << 16);
            o.y = (uint_t)f2bf(rf[t2].z) | ((uint_t)f2bf(rf[t2].w) << 16);
            reinterpret_cast<uint2*>(&s_mem[nc][i / 1200][0])[i % 1200] = o;
          }
        }
      }
    }
    __syncthreads();   // staged buffer ready for next iter; tail reads retired
  }
}

// ---------------- conv3+gi: 16 images/block (verified R11-R16) ----------------
__global__ __launch_bounds__(256) void conv3gi_kernel(
    const ushort_t* __restrict__ f2g, const ushort_t* __restrict__ w3bf,
    const ushort_t* __restrict__ wihb, const void* __restrict__ b3,
    const int* __restrict__ flags, float* __restrict__ gi, int img_base) {
  __shared__ __attribute__((aligned(16))) ushort_t f2b[16 * 592];
  __shared__ __attribute__((aligned(16))) ushort_t f3b[16 * 72];

  const int tid = threadIdx.x;
  const int wave = tid >> 6, lane = tid & 63;
  const int lrow = lane & 15, lk8 = lane >> 4;
  const int fw = flags[1];
  const int iloc0 = blockIdx.x * 16;

  for (int i = tid; i < 16 * 72; i += 256) {
    const int im_ = i / 72, off = i - im_ * 72;
    *reinterpret_cast<uint4*>(&f2b[im_ * 592 + off * 8]) =
        *reinterpret_cast<const uint4*>(&f2g[((size_t)img_base + iloc0 + im_) * 576 + off * 8]);
  }
  __syncthreads();

  {
    f32x4_t c3 = (f32x4_t){0.f, 0.f, 0.f, 0.f};
    const ushort_t* w3r = w3bf + (wave * 16 + lrow) * 576 + lk8 * 8;
#pragma unroll
    for (int ks = 0; ks < 18; ++ks) {
      short8_t a = ldsh8(&f2b[lrow * 592 + ks * 32 + lk8 * 8]);   // A row = img
      short8_t bv = ldg8(w3r + ks * 32);
      c3 = __builtin_amdgcn_mfma_f32_16x16x32_bf16(a, bv, c3, 0, 0, 0);
    }
    const int oc = wave * 16 + lrow;
    const float bias = ld1(b3, oc, fw);
#pragma unroll
    for (int r = 0; r < 4; ++r)
      f3b[(lk8 * 4 + r) * 72 + oc] = f2bf(fmaxf(c3[r] + bias, 0.f));
  }
  __syncthreads();

#pragma unroll
  for (int t = 0; t < 3; ++t) {
    const int nt = wave * 3 + t;
    f32x4_t g = (f32x4_t){0.f, 0.f, 0.f, 0.f};
#pragma unroll
    for (int ks = 0; ks < 2; ++ks) {
      short8_t a = ldsh8(&f3b[lrow * 72 + ks * 32 + lk8 * 8]);    // A row = img
      short8_t bv = ldg8(wihb + (nt * 16 + lrow) * 64 + ks * 32 + lk8 * 8);
      g = __builtin_amdgcn_mfma_f32_16x16x32_bf16(a, bv, g, 0, 0, 0);
    }
#pragma unroll
    for (int r = 0; r < 4; ++r)
      gi[((size_t)img_base + iloc0 + lk8 * 4 + r) * G3 + nt * 16 + lrow] = g[r];
  }
}

// ---------------- GRU: 1 wave/block, whh in 192 VGPRs (verified R13-R16) ----------------
__global__ __launch_bounds__(64, 1) void gru_kernel(
    const float* __restrict__ gi, const void* __restrict__ h0,
    const void* __restrict__ whh, const void* __restrict__ bih,
    const void* __restrict__ bhh, const int* __restrict__ flags,
    float* __restrict__ rnn, float* __restrict__ hout) {
  __shared__ float s_h[HID];
  const int j = threadIdx.x;
  const int s = blockIdx.x;
  const int fw = flags[1];

  float4 wr[16], wz[16], wn[16];
  if (fw) {
    const uint4* wb = reinterpret_cast<const uint4*>(whh);
#pragma unroll
    for (int i = 0; i < 8; ++i) {
      uint4 a = wb[(size_t)j * 8 + i];
      unpack2(a.x, wr[2 * i].x, wr[2 * i].y);
      unpack2(a.y, wr[2 * i].z, wr[2 * i].w);
      unpack2(a.z, wr[2 * i + 1].x, wr[2 * i + 1].y);
      unpack2(a.w, wr[2 * i + 1].z, wr[2 * i + 1].w);
      uint4 b = wb[(size_t)(64 + j) * 8 + i];
      unpack2(b.x, wz[2 * i].x, wz[2 * i].y);
      unpack2(b.y, wz[2 * i].z, wz[2 * i].w);
      unpack2(b.z, wz[2 * i + 1].x, wz[2 * i + 1].y);
      unpack2(b.w, wz[2 * i + 1].z, wz[2 * i + 1].w);
      uint4 c = wb[(size_t)(128 + j) * 8 + i];
      unpack2(c.x, wn[2 * i].x, wn[2 * i].y);
      unpack2(c.y, wn[2 * i].z, wn[2 * i].w);
      unpack2(c.z, wn[2 * i + 1].x, wn[2 * i + 1].y);
      unpack2(c.w, wn[2 * i + 1].z, wn[2 * i + 1].w);
    }
  } else {
    const float4* wf = reinterpret_cast<const float4*>(whh);
#pragma unroll
    for (int i = 0; i < 16; ++i) {
      wr[i] = wf[(size_t)j * 16 + i];
      wz[i] = wf[(size_t)(64 + j) * 16 + i];
      wn[i] = wf[(size_t)(128 + j) * 16 + i];
    }
  }

  float h = ld1(h0, s * HID + j, fw);
  s_h[j] = h;
  const float bir = ld1(bih, j, fw), biz = ld1(bih, 64 + j, fw), bin_ = ld1(bih, 128 + j, fw);
  const float bhr = ld1(bhh, j, fw), bhz = ld1(bhh, 64 + j, fw), bhn = ld1(bhh, 128 + j, fw);
  const int b = s >> 3, n = s & 7;
  const float* gbase = gi + ((size_t)b * Ll * Nn + n) * G3;
  float* rbase = rnn + ((size_t)b * Ll * Nn + n) * HID;
  WAVE_FENCE();

  float g0 = gbase[j], g1 = gbase[64 + j], g2 = gbase[128 + j];

  for (int l = 0; l < Ll; ++l) {
    float p0 = 0.f, p1 = 0.f, p2 = 0.f;
    if (l + 1 < Ll) {
      const float* gn = gbase + (size_t)(l + 1) * Nn * G3;
      p0 = gn[j]; p1 = gn[64 + j]; p2 = gn[128 + j];
    }
    float hr = bhr, hz = bhz, hn = bhn;
#pragma unroll
    for (int k = 0; k < 16; ++k) {
      float4 hv = *reinterpret_cast<const float4*>(&s_h[k * 4]);
      hr += wr[k].x * hv.x + wr[k].y * hv.y + wr[k].z * hv.z + wr[k].w * hv.w;
      hz += wz[k].x * hv.x + wz[k].y * hv.y + wz[k].z * hv.z + wz[k].w * hv.w;
      hn += wn[k].x * hv.x + wn[k].y * hv.y + wn[k].z * hv.z + wn[k].w * hv.w;
    }
    const float gr = g0 + bir + hr;
    const float gz = g1 + biz + hz;
    const float gn_ = g2 + bin_;
    const float r = 1.f / (1.f + __expf(-gr));
    const float z = 1.f / (1.f + __expf(-gz));
    const float nn_ = tanhf(gn_ + r * hn);
    h = (1.f - z) * nn_ + z * h;
    WAVE_FENCE();
    s_h[j] = h;
    rbase[(size_t)l * Nn * HID + j] = h;
    WAVE_FENCE();
    g0 = p0; g1 = p1; g2 = p2;
  }
  hout[(size_t)s * HID + j] = h;
}

// ---------------- FC: 256 blocks x 64 threads (verified R13-R16) ----------------
__global__ __launch_bounds__(64) void fc_kernel(
    const float* __restrict__ rnn, const void* __restrict__ fcw,
    const void* __restrict__ fcb, const int* __restrict__ flags,
    float* __restrict__ q) {
  __shared__ float s_w[NACT * HID];
  __shared__ float s_b[NACT];
  const int tid = threadIdx.x;
  const int fw = flags[1];
  for (int i = tid; i < NACT * HID; i += 64) s_w[i] = ld1(fcw, i, fw);
  if (tid < NACT) s_b[tid] = ld1(fcb, tid, fw);
  __syncthreads();
  const int row = blockIdx.x * 64 + tid;
  float x[64];
  const float4* xp = reinterpret_cast<const float4*>(rnn + (size_t)row * HID);
#pragma unroll
  for (int i = 0; i < 16; ++i) {
    float4 v = xp[i];
    x[4 * i] = v.x; x[4 * i + 1] = v.y; x[4 * i + 2] = v.z; x[4 * i + 3] = v.w;
  }
#pragma unroll
  for (int a = 0; a < NACT; ++a) {
    float v = s_b[a];
#pragma unroll
    for (int k = 0; k < 64; ++k) v += x[k] * s_w[a * 64 + k];
    q[(size_t)row * NACT + a] = v;
  }
}

extern "C" void kernel_launch(void* const* d_in, const int* in_sizes, int n_in,
                              void* d_out, int out_size, void* d_ws, size_t ws_size,
                              hipStream_t stream) {
  const void* obs = d_in[0];
  const void* h0  = d_in[1];
  const void* w1  = d_in[2];
  const void* b1  = d_in[3];
  const void* w2  = d_in[4];
  const void* b2  = d_in[5];
  const void* w3  = d_in[6];
  const void* b3  = d_in[7];
  const void* wih = d_in[8];
  const void* whh = d_in[9];
  const void* bih = d_in[10];
  const void* bhh = d_in[11];
  const void* fcw = d_in[12];
  const void* fcb = d_in[13];

  float* qout = (float*)d_out;                        // (B,L,N,8) f32
  float* hout = qout + (size_t)IMGS * NACT;           // (B,N,64)  f32

  // workspace layout (~35.8 MB; ws ~1.2 GB per R8 fill counters)
  char* wsb = (char*)d_ws;
  int*      flags  = (int*)wsb;                               // 16 B
  float*    gi     = (float*)(wsb + 16);                      // IMGS*192 f32
  float*    rnn    = gi + (size_t)IMGS * G3;                  // IMGS*64 f32
  ushort_t* w1pack = (ushort_t*)(rnn + (size_t)IMGS * HID);   // 6144 bf16
  ushort_t* w2pack = w1pack + 6144;                           // 32768 bf16
  ushort_t* w3bf   = w2pack + 32768;                          // 36864 bf16
  ushort_t* wihb   = w3bf + 36864;                            // 12288 bf16
  ushort_t* f2g    = wihb + 12288;                            // IMGS*576 bf16 (18.9 MB)

  detect_kernel<<<1, 256, 0, stream>>>((const ushort_t*)obs, (const ushort_t*)whh, flags);
  repack_kernel<<<144, 256, 0, stream>>>(w1, w2, w3, wih, flags, w1pack, w2pack, w3bf, wihb);

  conv12_kernel<<<CGRID, 256, 0, stream>>>(obs, w1pack, w2pack, b1, b2, flags, f2g);
  conv3gi_kernel<<<IMGS / 16, 256, 0, stream>>>(f2g, w3bf, wihb, b3, flags, gi, 0);

  gru_kernel<<<256, 64, 0, stream>>>(gi, h0, whh, bih, bhh, flags, rnn, hout);
  fc_kernel<<<IMGS / 64, 64, 0, stream>>>(rnn, fcw, fcb, flags, qout);
}

// Round 18
// 240.583 us; speedup vs baseline: 1.7812x; 1.7812x over previous
//
#include <hip/hip_runtime.h>
#include <math.h>

typedef unsigned short ushort_t;
typedef unsigned int uint_t;
typedef __attribute__((ext_vector_type(8))) short short8_t;   // 8 bf16 (4 VGPR)
typedef __attribute__((ext_vector_type(4))) float f32x4_t;    // MFMA accumulator

constexpr int Bb = 32, Ll = 64, Nn = 8;
constexpr int IMGS = Bb * Ll * Nn;          // 16384
constexpr int Cc = 3, Hh = 40, Ww = 40;
constexpr int HID = 64, G3 = 192, NACT = 8;

__device__ inline float bf2f(ushort_t u) {
  union { uint_t i; float f; } v; v.i = ((uint_t)u) << 16; return v.f;
}
__device__ inline ushort_t f2bf(float f) {   // RNE
  union { float f; uint_t u; } v; v.f = f;
  uint_t r = v.u + 0x7fffu + ((v.u >> 16) & 1u);
  return (ushort_t)(r >> 16);
}
__device__ inline void unpack2(uint_t u, float& lo, float& hi) {
  union { uint_t i; float f; } a, b;
  a.i = u << 16; b.i = u & 0xffff0000u;
  lo = a.f; hi = b.f;
}
__device__ inline float ld1(const void* p, int idx, int isbf) {
  return isbf ? bf2f(((const ushort_t*)p)[idx]) : ((const float*)p)[idx];
}
__device__ inline short8_t ldsh8(const ushort_t* p) {   // 16B from LDS (8B aligned)
  union { short8_t v; uint2 u[2]; } r;
  r.u[0] = *(const uint2*)p;
  r.u[1] = *(const uint2*)(p + 4);
  return r.v;
}
__device__ inline short8_t ldg8(const ushort_t* p) {    // 16B global
  union { short8_t v; uint4 u; } r;
  r.u = *(const uint4*)p;
  return r.v;
}
#define WAVE_FENCE() asm volatile("s_waitcnt lgkmcnt(0)" ::: "memory")

// ---------------- dtype detect (insurance) ----------------
__global__ __launch_bounds__(256) void detect_kernel(
    const ushort_t* __restrict__ obs, const ushort_t* __restrict__ whh,
    int* __restrict__ flags) {
  __shared__ int cnt[2];
  if (threadIdx.x < 2) cnt[threadIdx.x] = 0;
  __syncthreads();
  int bad0 = 0, bad1 = 0;
  for (int i = threadIdx.x; i < 4096; i += 256) {
    int e0 = (obs[i] >> 7) & 0xFF; if (e0 >= 0xC0) bad0++;
    int e1 = (whh[i] >> 7) & 0xFF; if (e1 >= 0xC0) bad1++;
  }
  atomicAdd(&cnt[0], bad0);
  atomicAdd(&cnt[1], bad1);
  __syncthreads();
  if (threadIdx.x == 0) { flags[0] = (cnt[0] <= 4); flags[1] = (cnt[1] <= 4); }
}

// ---------------- weight repack -> bf16 (verified R5-R17) ----------------
__global__ __launch_bounds__(256) void repack_kernel(
    const void* __restrict__ w1, const void* __restrict__ w2,
    const void* __restrict__ w3, const void* __restrict__ wih,
    const int* __restrict__ flags,
    ushort_t* __restrict__ w1pack, ushort_t* __restrict__ w2pack,
    ushort_t* __restrict__ w3bf, ushort_t* __restrict__ wihb) {
  const int fw = flags[1];
  int t = blockIdx.x * 256 + threadIdx.x;
  if (t < 6144) w1pack[t] = f2bf(ld1(w1, t, fw));
  if (t < 32768) {
    int oc = t >> 9, r = t & 511;
    int kykx = r >> 5, ic = r & 31;
    w2pack[t] = f2bf(ld1(w2, oc * 512 + ic * 16 + kykx, fw));
  }
  if (t < 36864) w3bf[t] = f2bf(ld1(w3, t, fw));
  if (t < 12288) wihb[t] = f2bf(ld1(wih, t, fw));
}

// ---------------- conv1+conv2: 2 images/block, 19.2 KB LDS, 8 blocks/CU ----------------
// Serial phases (NO prefetch held across barriers -> no spills). Cross-block overlap
// from 8 resident blocks/CU hides the staging latency.
// buf[im][0..4799]: bf16 obs -> f1 alias (<=3231); tail [3232..3807]: f2[oc*9+pix].
__global__ __launch_bounds__(256, 8) void conv12_kernel(
    const void* __restrict__ obs, const ushort_t* __restrict__ w1pack,
    const ushort_t* __restrict__ w2pack,
    const void* __restrict__ b1, const void* __restrict__ b2,
    const int* __restrict__ flags, ushort_t* __restrict__ f2g) {
  __shared__ __attribute__((aligned(16))) ushort_t s_mem[2][4800];   // 19.2 KB

  const int tid = threadIdx.x;
  const int wave = tid >> 6, lane = tid & 63;
  const int lrow = lane & 15, lk8 = lane >> 4;
  const int im = wave >> 1, half = wave & 1;          // conv1: image, m-half
  const int fobs = flags[0], fw = flags[1];
  const int img0 = blockIdx.x * 2;

  // ---- stage 2 images -> bf16 LDS (coalesced, small batches: <=20 transient VGPR) ----
  if (fobs) {
    const uint4* src = reinterpret_cast<const uint4*>((const ushort_t*)obs + (size_t)img0 * 4800);
#pragma unroll
    for (int t2 = 0; t2 < 5; ++t2) {                   // 1200 uint4
      const int i = t2 * 256 + tid;
      if (i < 1200) reinterpret_cast<uint4*>(&s_mem[i / 600][0])[i % 600] = src[i];
    }
  } else {
    const float4* src = reinterpret_cast<const float4*>((const float*)obs + (size_t)img0 * 4800);
#pragma unroll
    for (int bb = 0; bb < 2; ++bb) {                   // 2400 float4, 2 batches of 5
      float4 r[5];
#pragma unroll
      for (int t2 = 0; t2 < 5; ++t2) {
        const int i = (bb * 5 + t2) * 256 + tid;
        r[t2] = src[i < 2400 ? i : 2399];
      }
#pragma unroll
      for (int t2 = 0; t2 < 5; ++t2) {
        const int i = (bb * 5 + t2) * 256 + tid;
        if (i < 2400) {
          uint2 o;
          o.x = (uint_t)f2bf(r[t2].x) | ((uint_t)f2bf(r[t2].y) << 16);
          o.y = (uint_t)f2bf(r[t2].z) | ((uint_t)f2bf(r[t2].w) << 16);
          reinterpret_cast<uint2*>(&s_mem[i / 1200][0])[i % 1200] = o;
        }
      }
    }
  }
  __syncthreads();

  // ---- conv1: 2 waves per image, M-half = 48 rows, N=32, K=192 ----
  ushort_t* si = &s_mem[im][0];
  {
    int ab[3];
#pragma unroll
    for (int t = 0; t < 3; ++t) {
      int p = (half * 3 + t) * 16 + lrow; if (p > 80) p = 80;
      ab[t] = (p / 9) * 160 + (p % 9) * 4;
    }
    f32x4_t acc[2][3];
#pragma unroll
    for (int nt = 0; nt < 2; ++nt)
#pragma unroll
      for (int t = 0; t < 3; ++t) acc[nt][t] = (f32x4_t){0.f, 0.f, 0.f, 0.f};
    const ushort_t* w1r = w1pack + lrow * 192 + lk8 * 8;
#pragma unroll
    for (int ks = 0; ks < 6; ++ks) {
      const int g = ks * 4 + lk8;                       // k-octet 0..23
      const int aoff = (g >> 3) * 1600 + (g & 7) * 40;  // ic*1600 + ky*40
      short8_t b0 = ldg8(w1r + ks * 32);
      short8_t b1v = ldg8(w1r + 16 * 192 + ks * 32);
#pragma unroll
      for (int t = 0; t < 3; ++t) {
        short8_t a = ldsh8(&si[aoff + ab[t]]);
        acc[0][t] = __builtin_amdgcn_mfma_f32_16x16x32_bf16(a, b0, acc[0][t], 0, 0, 0);
        acc[1][t] = __builtin_amdgcn_mfma_f32_16x16x32_bf16(a, b1v, acc[1][t], 0, 0, 0);
      }
    }
    __syncthreads();   // both waves' obs reads done before alias-write
    const float bz0 = ld1(b1, lrow, fw), bz1 = ld1(b1, 16 + lrow, fw);
#pragma unroll
    for (int t = 0; t < 3; ++t) {
#pragma unroll
      for (int r = 0; r < 4; ++r) {
        const int p = (half * 3 + t) * 16 + lk8 * 4 + r;
        if (p < 81) {
          si[p * 40 + lrow]      = f2bf(fmaxf(acc[0][t][r] + bz0, 0.f));
          si[p * 40 + 16 + lrow] = f2bf(fmaxf(acc[1][t][r] + bz1, 0.f));
        }
      }
    }
  }
  __syncthreads();   // f1 complete & visible

  // ---- conv2: M=18(pad32) x N=16 (wave's oc-tile) x K=512; f2 -> LDS tails ----
  {
    int imgr[2], pbx[2];
#pragma unroll
    for (int mt = 0; mt < 2; ++mt) {
      int row = mt * 16 + lrow; if (row > 17) row = 17;
      const int ir = row / 9, p2 = row - ir * 9;
      imgr[mt] = ir;
      pbx[mt] = (p2 / 3) * 18 + (p2 % 3) * 2;           // (oy*2)*9 + ox*2
    }
    f32x4_t acc[2];
#pragma unroll
    for (int mt = 0; mt < 2; ++mt) acc[mt] = (f32x4_t){0.f, 0.f, 0.f, 0.f};
    const ushort_t* w2r = w2pack + (wave * 16 + lrow) * 512 + lk8 * 8;
#pragma unroll
    for (int s = 0; s < 16; ++s) {                      // s = ky*4+kx
      const int po = (s >> 2) * 9 + (s & 3);
      short8_t bv = ldg8(w2r + s * 32);
      short8_t a0 = ldsh8(&s_mem[imgr[0]][(pbx[0] + po) * 40 + lk8 * 8]);
      short8_t a1 = ldsh8(&s_mem[imgr[1]][(pbx[1] + po) * 40 + lk8 * 8]);
      acc[0] = __builtin_amdgcn_mfma_f32_16x16x32_bf16(a0, bv, acc[0], 0, 0, 0);
      acc[1] = __builtin_amdgcn_mfma_f32_16x16x32_bf16(a1, bv, acc[1], 0, 0, 0);
    }
    const int oc = wave * 16 + lrow;
    const float b2v = ld1(b2, oc, fw);
#pragma unroll
    for (int mt = 0; mt < 2; ++mt) {
#pragma unroll
      for (int r = 0; r < 4; ++r) {
        const int row = mt * 16 + lk8 * 4 + r;
        if (row < 18) {
          const int ir = row / 9, pp = row - ir * 9;
          s_mem[ir][3232 + oc * 9 + pp] = f2bf(fmaxf(acc[mt][r] + b2v, 0.f));
        }
      }
    }
  }
  __syncthreads();   // f2 tails visible

  // ---- coalesced f2 -> global (144 uint4) ----
  if (tid < 144) {
    const int im_ = tid / 72, off = tid - im_ * 72;
    *reinterpret_cast<uint4*>(&f2g[(size_t)(img0 + im_) * 576 + off * 8]) =
        *reinterpret_cast<const uint4*>(&s_mem[im_][3232 + off * 8]);
  }
}

// ---------------- conv3+gi: 16 images/block (verified R11-R16) ----------------
__global__ __launch_bounds__(256) void conv3gi_kernel(
    const ushort_t* __restrict__ f2g, const ushort_t* __restrict__ w3bf,
    const ushort_t* __restrict__ wihb, const void* __restrict__ b3,
    const int* __restrict__ flags, float* __restrict__ gi, int img_base) {
  __shared__ __attribute__((aligned(16))) ushort_t f2b[16 * 592];
  __shared__ __attribute__((aligned(16))) ushort_t f3b[16 * 72];

  const int tid = threadIdx.x;
  const int wave = tid >> 6, lane = tid & 63;
  const int lrow = lane & 15, lk8 = lane >> 4;
  const int fw = flags[1];
  const int iloc0 = blockIdx.x * 16;

  for (int i = tid; i < 16 * 72; i += 256) {
    const int im_ = i / 72, off = i - im_ * 72;
    *reinterpret_cast<uint4*>(&f2b[im_ * 592 + off * 8]) =
        *reinterpret_cast<const uint4*>(&f2g[((size_t)img_base + iloc0 + im_) * 576 + off * 8]);
  }
  __syncthreads();

  {
    f32x4_t c3 = (f32x4_t){0.f, 0.f, 0.f, 0.f};
    const ushort_t* w3r = w3bf + (wave * 16 + lrow) * 576 + lk8 * 8;
#pragma unroll
    for (int ks = 0; ks < 18; ++ks) {
      short8_t a = ldsh8(&f2b[lrow * 592 + ks * 32 + lk8 * 8]);   // A row = img
      short8_t bv = ldg8(w3r + ks * 32);
      c3 = __builtin_amdgcn_mfma_f32_16x16x32_bf16(a, bv, c3, 0, 0, 0);
    }
    const int oc = wave * 16 + lrow;
    const float bias = ld1(b3, oc, fw);
#pragma unroll
    for (int r = 0; r < 4; ++r)
      f3b[(lk8 * 4 + r) * 72 + oc] = f2bf(fmaxf(c3[r] + bias, 0.f));
  }
  __syncthreads();

#pragma unroll
  for (int t = 0; t < 3; ++t) {
    const int nt = wave * 3 + t;
    f32x4_t g = (f32x4_t){0.f, 0.f, 0.f, 0.f};
#pragma unroll
    for (int ks = 0; ks < 2; ++ks) {
      short8_t a = ldsh8(&f3b[lrow * 72 + ks * 32 + lk8 * 8]);    // A row = img
      short8_t bv = ldg8(wihb + (nt * 16 + lrow) * 64 + ks * 32 + lk8 * 8);
      g = __builtin_amdgcn_mfma_f32_16x16x32_bf16(a, bv, g, 0, 0, 0);
    }
#pragma unroll
    for (int r = 0; r < 4; ++r)
      gi[((size_t)img_base + iloc0 + lk8 * 4 + r) * G3 + nt * 16 + lrow] = g[r];
  }
}

// ---------------- GRU: 1 wave/block, whh in 192 VGPRs (verified R13-R16) ----------------
__global__ __launch_bounds__(64, 1) void gru_kernel(
    const float* __restrict__ gi, const void* __restrict__ h0,
    const void* __restrict__ whh, const void* __restrict__ bih,
    const void* __restrict__ bhh, const int* __restrict__ flags,
    float* __restrict__ rnn, float* __restrict__ hout) {
  __shared__ float s_h[HID];
  const int j = threadIdx.x;
  const int s = blockIdx.x;
  const int fw = flags[1];

  float4 wr[16], wz[16], wn[16];
  if (fw) {
    const uint4* wb = reinterpret_cast<const uint4*>(whh);
#pragma unroll
    for (int i = 0; i < 8; ++i) {
      uint4 a = wb[(size_t)j * 8 + i];
      unpack2(a.x, wr[2 * i].x, wr[2 * i].y);
      unpack2(a.y, wr[2 * i].z, wr[2 * i].w);
      unpack2(a.z, wr[2 * i + 1].x, wr[2 * i + 1].y);
      unpack2(a.w, wr[2 * i + 1].z, wr[2 * i + 1].w);
      uint4 b = wb[(size_t)(64 + j) * 8 + i];
      unpack2(b.x, wz[2 * i].x, wz[2 * i].y);
      unpack2(b.y, wz[2 * i].z, wz[2 * i].w);
      unpack2(b.z, wz[2 * i + 1].x, wz[2 * i + 1].y);
      unpack2(b.w, wz[2 * i + 1].z, wz[2 * i + 1].w);
      uint4 c = wb[(size_t)(128 + j) * 8 + i];
      unpack2(c.x, wn[2 * i].x, wn[2 * i].y);
      unpack2(c.y, wn[2 * i].z, wn[2 * i].w);
      unpack2(c.z, wn[2 * i + 1].x, wn[2 * i + 1].y);
      unpack2(c.w, wn[2 * i + 1].z, wn[2 * i + 1].w);
    }
  } else {
    const float4* wf = reinterpret_cast<const float4*>(whh);
#pragma unroll
    for (int i = 0; i < 16; ++i) {
      wr[i] = wf[(size_t)j * 16 + i];
      wz[i] = wf[(size_t)(64 + j) * 16 + i];
      wn[i] = wf[(size_t)(128 + j) * 16 + i];
    }
  }

  float h = ld1(h0, s * HID + j, fw);
  s_h[j] = h;
  const float bir = ld1(bih, j, fw), biz = ld1(bih, 64 + j, fw), bin_ = ld1(bih, 128 + j, fw);
  const float bhr = ld1(bhh, j, fw), bhz = ld1(bhh, 64 + j, fw), bhn = ld1(bhh, 128 + j, fw);
  const int b = s >> 3, n = s & 7;
  const float* gbase = gi + ((size_t)b * Ll * Nn + n) * G3;
  float* rbase = rnn + ((size_t)b * Ll * Nn + n) * HID;
  WAVE_FENCE();

  float g0 = gbase[j], g1 = gbase[64 + j], g2 = gbase[128 + j];

  for (int l = 0; l < Ll; ++l) {
    float p0 = 0.f, p1 = 0.f, p2 = 0.f;
    if (l + 1 < Ll) {
      const float* gn = gbase + (size_t)(l + 1) * Nn * G3;
      p0 = gn[j]; p1 = gn[64 + j]; p2 = gn[128 + j];
    }
    float hr = bhr, hz = bhz, hn = bhn;
#pragma unroll
    for (int k = 0; k < 16; ++k) {
      float4 hv = *reinterpret_cast<const float4*>(&s_h[k * 4]);
      hr += wr[k].x * hv.x + wr[k].y * hv.y + wr[k].z * hv.z + wr[k].w * hv.w;
      hz += wz[k].x * hv.x + wz[k].y * hv.y + wz[k].z * hv.z + wz[k].w * hv.w;
      hn += wn[k].x * hv.x + wn[k].y * hv.y + wn[k].z * hv.z + wn[k].w * hv.w;
    }
    const float gr = g0 + bir + hr;
    const float gz = g1 + biz + hz;
    const float gn_ = g2 + bin_;
    const float r = 1.f / (1.f + __expf(-gr));
    const float z = 1.f / (1.f + __expf(-gz));
    const float nn_ = tanhf(gn_ + r * hn);
    h = (1.f - z) * nn_ + z * h;
    WAVE_FENCE();
    s_h[j] = h;
    rbase[(size_t)l * Nn * HID + j] = h;
    WAVE_FENCE();
    g0 = p0; g1 = p1; g2 = p2;
  }
  hout[(size_t)s * HID + j] = h;
}

// ---------------- FC: 256 blocks x 64 threads (verified R13-R16) ----------------
__global__ __launch_bounds__(64) void fc_kernel(
    const float* __restrict__ rnn, const void* __restrict__ fcw,
    const void* __restrict__ fcb, const int* __restrict__ flags,
    float* __restrict__ q) {
  __shared__ float s_w[NACT * HID];
  __shared__ float s_b[NACT];
  const int tid = threadIdx.x;
  const int fw = flags[1];
  for (int i = tid; i < NACT * HID; i += 64) s_w[i] = ld1(fcw, i, fw);
  if (tid < NACT) s_b[tid] = ld1(fcb, tid, fw);
  __syncthreads();
  const int row = blockIdx.x * 64 + tid;
  float x[64];
  const float4* xp = reinterpret_cast<const float4*>(rnn + (size_t)row * HID);
#pragma unroll
  for (int i = 0; i < 16; ++i) {
    float4 v = xp[i];
    x[4 * i] = v.x; x[4 * i + 1] = v.y; x[4 * i + 2] = v.z; x[4 * i + 3] = v.w;
  }
#pragma unroll
  for (int a = 0; a < NACT; ++a) {
    float v = s_b[a];
#pragma unroll
    for (int k = 0; k < 64; ++k) v += x[k] * s_w[a * 64 + k];
    q[(size_t)row * NACT + a] = v;
  }
}

extern "C" void kernel_launch(void* const* d_in, const int* in_sizes, int n_in,
                              void* d_out, int out_size, void* d_ws, size_t ws_size,
                              hipStream_t stream) {
  const void* obs = d_in[0];
  const void* h0  = d_in[1];
  const void* w1  = d_in[2];
  const void* b1  = d_in[3];
  const void* w2  = d_in[4];
  const void* b2  = d_in[5];
  const void* w3  = d_in[6];
  const void* b3  = d_in[7];
  const void* wih = d_in[8];
  const void* whh = d_in[9];
  const void* bih = d_in[10];
  const void* bhh = d_in[11];
  const void* fcw = d_in[12];
  const void* fcb = d_in[13];

  float* qout = (float*)d_out;                        // (B,L,N,8) f32
  float* hout = qout + (size_t)IMGS * NACT;           // (B,N,64)  f32

  // workspace layout (~35.8 MB; ws ~1.2 GB per R8 fill counters)
  char* wsb = (char*)d_ws;
  int*      flags  = (int*)wsb;                               // 16 B
  float*    gi     = (float*)(wsb + 16);                      // IMGS*192 f32
  float*    rnn    = gi + (size_t)IMGS * G3;                  // IMGS*64 f32
  ushort_t* w1pack = (ushort_t*)(rnn + (size_t)IMGS * HID);   // 6144 bf16
  ushort_t* w2pack = w1pack + 6144;                           // 32768 bf16
  ushort_t* w3bf   = w2pack + 32768;                          // 36864 bf16
  ushort_t* wihb   = w3bf + 36864;                            // 12288 bf16
  ushort_t* f2g    = wihb + 12288;                            // IMGS*576 bf16 (18.9 MB)

  detect_kernel<<<1, 256, 0, stream>>>((const ushort_t*)obs, (const ushort_t*)whh, flags);
  repack_kernel<<<144, 256, 0, stream>>>(w1, w2, w3, wih, flags, w1pack, w2pack, w3bf, wihb);

  conv12_kernel<<<IMGS / 2, 256, 0, stream>>>(obs, w1pack, w2pack, b1, b2, flags, f2g);
  conv3gi_kernel<<<IMGS / 16, 256, 0, stream>>>(f2g, w3bf, wihb, b3, flags, gi, 0);

  gru_kernel<<<256, 64, 0, stream>>>(gi, h0, whh, bih, bhh, flags, rnn, hout);
  fc_kernel<<<IMGS / 64, 64, 0, stream>>>(rnn, fcw, fcb, flags, qout);
}

// Round 19
// 196.603 us; speedup vs baseline: 2.1796x; 1.2237x over previous
//
#include <hip/hip_runtime.h>
#include <math.h>

typedef unsigned short ushort_t;
typedef unsigned int uint_t;
typedef __attribute__((ext_vector_type(8))) short short8_t;   // 8 bf16 (4 VGPR)
typedef __attribute__((ext_vector_type(4))) float f32x4_t;    // MFMA accumulator

constexpr int Bb = 32, Ll = 64, Nn = 8;
constexpr int IMGS = Bb * Ll * Nn;          // 16384
constexpr int Cc = 3, Hh = 40, Ww = 40;
constexpr int HID = 64, G3 = 192, NACT = 8;

__device__ inline float bf2f(ushort_t u) {
  union { uint_t i; float f; } v; v.i = ((uint_t)u) << 16; return v.f;
}
__device__ inline ushort_t f2bf(float f) {   // RNE
  union { float f; uint_t u; } v; v.f = f;
  uint_t r = v.u + 0x7fffu + ((v.u >> 16) & 1u);
  return (ushort_t)(r >> 16);
}
__device__ inline void unpack2(uint_t u, float& lo, float& hi) {
  union { uint_t i; float f; } a, b;
  a.i = u << 16; b.i = u & 0xffff0000u;
  lo = a.f; hi = b.f;
}
__device__ inline float ld1(const void* p, int idx, int isbf) {
  return isbf ? bf2f(((const ushort_t*)p)[idx]) : ((const float*)p)[idx];
}
__device__ inline short8_t ldsh8(const ushort_t* p) {   // 16B from LDS (8B aligned)
  union { short8_t v; uint2 u[2]; } r;
  r.u[0] = *(const uint2*)p;
  r.u[1] = *(const uint2*)(p + 4);
  return r.v;
}
__device__ inline short8_t ldg8(const ushort_t* p) {    // 16B global
  union { short8_t v; uint4 u; } r;
  r.u = *(const uint4*)p;
  return r.v;
}
#define WAVE_FENCE() asm volatile("s_waitcnt lgkmcnt(0)" ::: "memory")

// ---------------- dtype detect (insurance) ----------------
__global__ __launch_bounds__(256) void detect_kernel(
    const ushort_t* __restrict__ obs, const ushort_t* __restrict__ whh,
    int* __restrict__ flags) {
  __shared__ int cnt[2];
  if (threadIdx.x < 2) cnt[threadIdx.x] = 0;
  __syncthreads();
  int bad0 = 0, bad1 = 0;
  for (int i = threadIdx.x; i < 4096; i += 256) {
    int e0 = (obs[i] >> 7) & 0xFF; if (e0 >= 0xC0) bad0++;
    int e1 = (whh[i] >> 7) & 0xFF; if (e1 >= 0xC0) bad1++;
  }
  atomicAdd(&cnt[0], bad0);
  atomicAdd(&cnt[1], bad1);
  __syncthreads();
  if (threadIdx.x == 0) { flags[0] = (cnt[0] <= 4); flags[1] = (cnt[1] <= 4); }
}

// ---------------- weight repack -> bf16 (verified R5-R16) ----------------
__global__ __launch_bounds__(256) void repack_kernel(
    const void* __restrict__ w1, const void* __restrict__ w2,
    const void* __restrict__ w3, const void* __restrict__ wih,
    const int* __restrict__ flags,
    ushort_t* __restrict__ w1pack, ushort_t* __restrict__ w2pack,
    ushort_t* __restrict__ w3bf, ushort_t* __restrict__ wihb) {
  const int fw = flags[1];
  int t = blockIdx.x * 256 + threadIdx.x;
  if (t < 6144) w1pack[t] = f2bf(ld1(w1, t, fw));
  if (t < 32768) {
    int oc = t >> 9, r = t & 511;
    int kykx = r >> 5, ic = r & 31;
    w2pack[t] = f2bf(ld1(w2, oc * 512 + ic * 16 + kykx, fw));
  }
  if (t < 36864) w3bf[t] = f2bf(ld1(w3, t, fw));
  if (t < 12288) wihb[t] = f2bf(ld1(wih, t, fw));
}

// ---------------- fused conv1+conv2: 4 images/block (R16 verified best) ----------------
// f2 -> LDS tail (s_mem[im][3232..3807], disjoint from f1 <=3231),
// then ONE barrier + 288 coalesced uint4 global stores.
__global__ __launch_bounds__(256, 4) void conv12_kernel(
    const void* __restrict__ obs, const ushort_t* __restrict__ w1pack,
    const ushort_t* __restrict__ w2pack,
    const void* __restrict__ b1, const void* __restrict__ b2,
    const int* __restrict__ flags, ushort_t* __restrict__ f2g, int img_base) {
  __shared__ __attribute__((aligned(16))) ushort_t s_mem[4][4800];   // 38.4 KB

  const int tid = threadIdx.x;
  const int wave = tid >> 6, lane = tid & 63;
  const int lrow = lane & 15, lk8 = lane >> 4;
  const int fobs = flags[0], fw = flags[1];
  const int img0 = blockIdx.x * 4;

  // ---- stage 4 images -> bf16 LDS; register-batched (verified R11) ----
  if (fobs) {
    const uint4* src = reinterpret_cast<const uint4*>((const ushort_t*)obs + ((size_t)img_base + img0) * 4800);
    uint4 r[10];
#pragma unroll
    for (int it = 0; it < 10; ++it) {
      const int i = it * 256 + tid;
      r[it] = src[i < 2400 ? i : 2399];
    }
#pragma unroll
    for (int it = 0; it < 10; ++it) {
      const int i = it * 256 + tid;
      if (i < 2400) {
        const int im_ = i / 600, e = i - im_ * 600;
        reinterpret_cast<uint4*>(s_mem[im_])[e] = r[it];
      }
    }
  } else {
    const float4* src = reinterpret_cast<const float4*>((const float*)obs + ((size_t)img_base + img0) * 4800);
#pragma unroll
    for (int bb = 0; bb < 2; ++bb) {
      float4 r[10];
#pragma unroll
      for (int it = 0; it < 10; ++it) {
        const int i = (bb * 10 + it) * 256 + tid;
        r[it] = src[i < 4800 ? i : 4799];
      }
#pragma unroll
      for (int it = 0; it < 10; ++it) {
        const int i = (bb * 10 + it) * 256 + tid;
        if (i < 4800) {
          const int im_ = i / 1200, e = i - im_ * 1200;
          uint2 o;
          o.x = (uint_t)f2bf(r[it].x) | ((uint_t)f2bf(r[it].y) << 16);
          o.y = (uint_t)f2bf(r[it].z) | ((uint_t)f2bf(r[it].w) << 16);
          reinterpret_cast<uint2*>(s_mem[im_])[e] = o;
        }
      }
    }
  }
  __syncthreads();

  // ---- conv1 (verified): wave's own image, M=81(pad96) x N=32 x K=192 ----
  {
    ushort_t* si = s_mem[wave];
    int ab[6];
#pragma unroll
    for (int mt = 0; mt < 6; ++mt) {
      int p = mt * 16 + lrow; if (p > 80) p = 80;
      ab[mt] = (p / 9) * 160 + (p % 9) * 4;
    }
    f32x4_t acc[2][6];
#pragma unroll
    for (int nt = 0; nt < 2; ++nt)
#pragma unroll
      for (int mt = 0; mt < 6; ++mt) acc[nt][mt] = (f32x4_t){0.f, 0.f, 0.f, 0.f};
    const ushort_t* wr0 = w1pack + lrow * 192 + lk8 * 8;
#pragma unroll
    for (int ks = 0; ks < 6; ++ks) {
      const int g = ks * 4 + lk8;                       // k-octet 0..23
      const int aoff = (g >> 3) * 1600 + (g & 7) * 40;  // ic*1600 + ky*40
      short8_t b0 = ldg8(wr0 + ks * 32);
      short8_t b1v = ldg8(wr0 + 16 * 192 + ks * 32);
#pragma unroll
      for (int mt = 0; mt < 6; ++mt) {
        short8_t a = ldsh8(&si[aoff + ab[mt]]);
        acc[0][mt] = __builtin_amdgcn_mfma_f32_16x16x32_bf16(a, b0, acc[0][mt], 0, 0, 0);
        acc[1][mt] = __builtin_amdgcn_mfma_f32_16x16x32_bf16(a, b1v, acc[1][mt], 0, 0, 0);
      }
    }
    WAVE_FENCE();   // all s_in reads retired -> safe to alias-write f1
    const float bz0 = ld1(b1, lrow, fw), bz1 = ld1(b1, 16 + lrow, fw);
#pragma unroll
    for (int mt = 0; mt < 6; ++mt) {
#pragma unroll
      for (int r = 0; r < 4; ++r) {
        const int p = mt * 16 + lk8 * 4 + r;
        if (p < 81) {
          si[p * 40 + lrow]      = f2bf(fmaxf(acc[0][mt][r] + bz0, 0.f));
          si[p * 40 + 16 + lrow] = f2bf(fmaxf(acc[1][mt][r] + bz1, 0.f));
        }
      }
    }
  }
  __syncthreads();

  // ---- conv2: M=36 (4 img x 9 pix, pad48) x N=16 (wave's oc-tile) x K=512 ----
  // output -> LDS tail (disjoint from f1 region; no extra barrier needed here)
  {
    int imgr[3], pbx[3];
#pragma unroll
    for (int mt = 0; mt < 3; ++mt) {
      int row = mt * 16 + lrow; if (row > 35) row = 35;
      const int ir = row / 9, p2 = row - ir * 9;
      imgr[mt] = ir;
      pbx[mt] = (p2 / 3) * 18 + (p2 % 3) * 2;           // (oy*2)*9 + ox*2
    }
    f32x4_t acc[3];
#pragma unroll
    for (int mt = 0; mt < 3; ++mt) acc[mt] = (f32x4_t){0.f, 0.f, 0.f, 0.f};
    const ushort_t* w2r = w2pack + (wave * 16 + lrow) * 512 + lk8 * 8;
#pragma unroll
    for (int s = 0; s < 16; ++s) {                      // s = ky*4+kx
      const int po = (s >> 2) * 9 + (s & 3);
      short8_t bv = ldg8(w2r + s * 32);
      short8_t a0 = ldsh8(&s_mem[imgr[0]][(pbx[0] + po) * 40 + lk8 * 8]);
      short8_t a1 = ldsh8(&s_mem[imgr[1]][(pbx[1] + po) * 40 + lk8 * 8]);
      short8_t a2 = ldsh8(&s_mem[imgr[2]][(pbx[2] + po) * 40 + lk8 * 8]);
      acc[0] = __builtin_amdgcn_mfma_f32_16x16x32_bf16(a0, bv, acc[0], 0, 0, 0);
      acc[1] = __builtin_amdgcn_mfma_f32_16x16x32_bf16(a1, bv, acc[1], 0, 0, 0);
      acc[2] = __builtin_amdgcn_mfma_f32_16x16x32_bf16(a2, bv, acc[2], 0, 0, 0);
    }
    const int oc = wave * 16 + lrow;
    const float bias = ld1(b2, oc, fw);
#pragma unroll
    for (int mt = 0; mt < 3; ++mt) {
#pragma unroll
      for (int r = 0; r < 4; ++r) {
        const int row = mt * 16 + lk8 * 4 + r;
        if (row < 36) {
          const int ir = row / 9, pp = row - ir * 9;
          s_mem[ir][3232 + oc * 9 + pp] = f2bf(fmaxf(acc[mt][r] + bias, 0.f));
        }
      }
    }
  }
  __syncthreads();   // f2 tails visible to all threads

  // ---- coalesced f2 -> global: 288 uint4 (16B) stores, fully coalesced ----
#pragma unroll
  for (int t2 = 0; t2 < 2; ++t2) {
    const int i = t2 * 256 + tid;
    if (i < 288) {
      const int im_ = i / 72, off = i - im_ * 72;
      *reinterpret_cast<uint4*>(&f2g[((size_t)img_base + img0 + im_) * 576 + off * 8]) =
          *reinterpret_cast<const uint4*>(&s_mem[im_][3232 + off * 8]);
    }
  }
}

// ---------------- conv3+gi: 16 images/block (verified R11-R16) ----------------
__global__ __launch_bounds__(256) void conv3gi_kernel(
    const ushort_t* __restrict__ f2g, const ushort_t* __restrict__ w3bf,
    const ushort_t* __restrict__ wihb, const void* __restrict__ b3,
    const int* __restrict__ flags, float* __restrict__ gi, int img_base) {
  __shared__ __attribute__((aligned(16))) ushort_t f2b[16 * 592];
  __shared__ __attribute__((aligned(16))) ushort_t f3b[16 * 72];

  const int tid = threadIdx.x;
  const int wave = tid >> 6, lane = tid & 63;
  const int lrow = lane & 15, lk8 = lane >> 4;
  const int fw = flags[1];
  const int iloc0 = blockIdx.x * 16;

  for (int i = tid; i < 16 * 72; i += 256) {
    const int im_ = i / 72, off = i - im_ * 72;
    *reinterpret_cast<uint4*>(&f2b[im_ * 592 + off * 8]) =
        *reinterpret_cast<const uint4*>(&f2g[((size_t)img_base + iloc0 + im_) * 576 + off * 8]);
  }
  __syncthreads();

  {
    f32x4_t c3 = (f32x4_t){0.f, 0.f, 0.f, 0.f};
    const ushort_t* w3r = w3bf + (wave * 16 + lrow) * 576 + lk8 * 8;
#pragma unroll
    for (int ks = 0; ks < 18; ++ks) {
      short8_t a = ldsh8(&f2b[lrow * 592 + ks * 32 + lk8 * 8]);   // A row = img
      short8_t bv = ldg8(w3r + ks * 32);
      c3 = __builtin_amdgcn_mfma_f32_16x16x32_bf16(a, bv, c3, 0, 0, 0);
    }
    const int oc = wave * 16 + lrow;
    const float bias = ld1(b3, oc, fw);
#pragma unroll
    for (int r = 0; r < 4; ++r)
      f3b[(lk8 * 4 + r) * 72 + oc] = f2bf(fmaxf(c3[r] + bias, 0.f));
  }
  __syncthreads();

#pragma unroll
  for (int t = 0; t < 3; ++t) {
    const int nt = wave * 3 + t;
    f32x4_t g = (f32x4_t){0.f, 0.f, 0.f, 0.f};
#pragma unroll
    for (int ks = 0; ks < 2; ++ks) {
      short8_t a = ldsh8(&f3b[lrow * 72 + ks * 32 + lk8 * 8]);    // A row = img
      short8_t bv = ldg8(wihb + (nt * 16 + lrow) * 64 + ks * 32 + lk8 * 8);
      g = __builtin_amdgcn_mfma_f32_16x16x32_bf16(a, bv, g, 0, 0, 0);
    }
#pragma unroll
    for (int r = 0; r < 4; ++r)
      gi[((size_t)img_base + iloc0 + lk8 * 4 + r) * G3 + nt * 16 + lrow] = g[r];
  }
}

// ---------------- GRU: 1 wave/block, whh in 192 VGPRs (verified R13-R16) ----------------
__global__ __launch_bounds__(64, 1) void gru_kernel(
    const float* __restrict__ gi, const void* __restrict__ h0,
    const void* __restrict__ whh, const void* __restrict__ bih,
    const void* __restrict__ bhh, const int* __restrict__ flags,
    float* __restrict__ rnn, float* __restrict__ hout) {
  __shared__ float s_h[HID];
  const int j = threadIdx.x;
  const int s = blockIdx.x;
  const int fw = flags[1];

  float4 wr[16], wz[16], wn[16];
  if (fw) {
    const uint4* wb = reinterpret_cast<const uint4*>(whh);
#pragma unroll
    for (int i = 0; i < 8; ++i) {
      uint4 a = wb[(size_t)j * 8 + i];
      unpack2(a.x, wr[2 * i].x, wr[2 * i].y);
      unpack2(a.y, wr[2 * i].z, wr[2 * i].w);
      unpack2(a.z, wr[2 * i + 1].x, wr[2 * i + 1].y);
      unpack2(a.w, wr[2 * i + 1].z, wr[2 * i + 1].w);
      uint4 b = wb[(size_t)(64 + j) * 8 + i];
      unpack2(b.x, wz[2 * i].x, wz[2 * i].y);
      unpack2(b.y, wz[2 * i].z, wz[2 * i].w);
      unpack2(b.z, wz[2 * i + 1].x, wz[2 * i + 1].y);
      unpack2(b.w, wz[2 * i + 1].z, wz[2 * i + 1].w);
      uint4 c = wb[(size_t)(128 + j) * 8 + i];
      unpack2(c.x, wn[2 * i].x, wn[2 * i].y);
      unpack2(c.y, wn[2 * i].z, wn[2 * i].w);
      unpack2(c.z, wn[2 * i + 1].x, wn[2 * i + 1].y);
      unpack2(c.w, wn[2 * i + 1].z, wn[2 * i + 1].w);
    }
  } else {
    const float4* wf = reinterpret_cast<const float4*>(whh);
#pragma unroll
    for (int i = 0; i < 16; ++i) {
      wr[i] = wf[(size_t)j * 16 + i];
      wz[i] = wf[(size_t)(64 + j) * 16 + i];
      wn[i] = wf[(size_t)(128 + j) * 16 + i];
    }
  }

  float h = ld1(h0, s * HID + j, fw);
  s_h[j] = h;
  const float bir = ld1(bih, j, fw), biz = ld1(bih, 64 + j, fw), bin_ = ld1(bih, 128 + j, fw);
  const float bhr = ld1(bhh, j, fw), bhz = ld1(bhh, 64 + j, fw), bhn = ld1(bhh, 128 + j, fw);
  const int b = s >> 3, n = s & 7;
  const float* gbase = gi + ((size_t)b * Ll * Nn + n) * G3;
  float* rbase = rnn + ((size_t)b * Ll * Nn + n) * HID;
  WAVE_FENCE();

  float g0 = gbase[j], g1 = gbase[64 + j], g2 = gbase[128 + j];

  for (int l = 0; l < Ll; ++l) {
    float p0 = 0.f, p1 = 0.f, p2 = 0.f;
    if (l + 1 < Ll) {
      const float* gn = gbase + (size_t)(l + 1) * Nn * G3;
      p0 = gn[j]; p1 = gn[64 + j]; p2 = gn[128 + j];
    }
    float hr = bhr, hz = bhz, hn = bhn;
#pragma unroll
    for (int k = 0; k < 16; ++k) {
      float4 hv = *reinterpret_cast<const float4*>(&s_h[k * 4]);
      hr += wr[k].x * hv.x + wr[k].y * hv.y + wr[k].z * hv.z + wr[k].w * hv.w;
      hz += wz[k].x * hv.x + wz[k].y * hv.y + wz[k].z * hv.z + wz[k].w * hv.w;
      hn += wn[k].x * hv.x + wn[k].y * hv.y + wn[k].z * hv.z + wn[k].w * hv.w;
    }
    const float gr = g0 + bir + hr;
    const float gz = g1 + biz + hz;
    const float gn_ = g2 + bin_;
    const float r = 1.f / (1.f + __expf(-gr));
    const float z = 1.f / (1.f + __expf(-gz));
    const float nn_ = tanhf(gn_ + r * hn);
    h = (1.f - z) * nn_ + z * h;
    WAVE_FENCE();
    s_h[j] = h;
    rbase[(size_t)l * Nn * HID + j] = h;
    WAVE_FENCE();
    g0 = p0; g1 = p1; g2 = p2;
  }
  hout[(size_t)s * HID + j] = h;
}

// ---------------- FC: 256 blocks x 64 threads (verified R13-R16) ----------------
__global__ __launch_bounds__(64) void fc_kernel(
    const float* __restrict__ rnn, const void* __restrict__ fcw,
    const void* __restrict__ fcb, const int* __restrict__ flags,
    float* __restrict__ q) {
  __shared__ float s_w[NACT * HID];
  __shared__ float s_b[NACT];
  const int tid = threadIdx.x;
  const int fw = flags[1];
  for (int i = tid; i < NACT * HID; i += 64) s_w[i] = ld1(fcw, i, fw);
  if (tid < NACT) s_b[tid] = ld1(fcb, tid, fw);
  __syncthreads();
  const int row = blockIdx.x * 64 + tid;
  float x[64];
  const float4* xp = reinterpret_cast<const float4*>(rnn + (size_t)row * HID);
#pragma unroll
  for (int i = 0; i < 16; ++i) {
    float4 v = xp[i];
    x[4 * i] = v.x; x[4 * i + 1] = v.y; x[4 * i + 2] = v.z; x[4 * i + 3] = v.w;
  }
#pragma unroll
  for (int a = 0; a < NACT; ++a) {
    float v = s_b[a];
#pragma unroll
    for (int k = 0; k < 64; ++k) v += x[k] * s_w[a * 64 + k];
    q[(size_t)row * NACT + a] = v;
  }
}

extern "C" void kernel_launch(void* const* d_in, const int* in_sizes, int n_in,
                              void* d_out, int out_size, void* d_ws, size_t ws_size,
                              hipStream_t stream) {
  const void* obs = d_in[0];
  const void* h0  = d_in[1];
  const void* w1  = d_in[2];
  const void* b1  = d_in[3];
  const void* w2  = d_in[4];
  const void* b2  = d_in[5];
  const void* w3  = d_in[6];
  const void* b3  = d_in[7];
  const void* wih = d_in[8];
  const void* whh = d_in[9];
  const void* bih = d_in[10];
  const void* bhh = d_in[11];
  const void* fcw = d_in[12];
  const void* fcb = d_in[13];

  float* qout = (float*)d_out;                        // (B,L,N,8) f32
  float* hout = qout + (size_t)IMGS * NACT;           // (B,N,64)  f32

  // workspace layout (~35.8 MB; ws ~1.2 GB per R8 fill counters)
  char* wsb = (char*)d_ws;
  int*      flags  = (int*)wsb;                               // 16 B
  float*    gi     = (float*)(wsb + 16);                      // IMGS*192 f32
  float*    rnn    = gi + (size_t)IMGS * G3;                  // IMGS*64 f32
  ushort_t* w1pack = (ushort_t*)(rnn + (size_t)IMGS * HID);   // 6144 bf16
  ushort_t* w2pack = w1pack + 6144;                           // 32768 bf16
  ushort_t* w3bf   = w2pack + 32768;                          // 36864 bf16
  ushort_t* wihb   = w3bf + 36864;                            // 12288 bf16
  ushort_t* f2g    = wihb + 12288;                            // IMGS*576 bf16 (18.9 MB)

  detect_kernel<<<1, 256, 0, stream>>>((const ushort_t*)obs, (const ushort_t*)whh, flags);
  repack_kernel<<<144, 256, 0, stream>>>(w1, w2, w3, wih, flags, w1pack, w2pack, w3bf, wihb);

  conv12_kernel<<<IMGS / 4, 256, 0, stream>>>(obs, w1pack, w2pack, b1, b2, flags, f2g, 0);
  conv3gi_kernel<<<IMGS / 16, 256, 0, stream>>>(f2g, w3bf, wihb, b3, flags, gi, 0);

  gru_kernel<<<256, 64, 0, stream>>>(gi, h0, whh, bih, bhh, flags, rnn, hout);
  fc_kernel<<<IMGS / 64, 64, 0, stream>>>(rnn, fcw, fcb, flags, qout);
}